// Round 1
// baseline (223.421 us; speedup 1.0000x reference)
//
#include <hip/hip_runtime.h>
#include <math.h>

#define NB    16
#define NAg   3
#define NCg   85
#define NCLS  80
#define NGg   76
#define NSp   (NGg*NGg)     // 5776
#define NCELL (NAg*NSp)     // 17328
#define NBOX  50
#define INCH  256

// ws layout (bytes)
#define ACC_OFF  0                          // 8 floats (use 4: xy, wh, obj, cls)
#define WIN_OFF  32                         // NB*NCELL ints = 1108992
#define PRED_OFF (32 + NB*NCELL*4)          // 1109024 ; NB*15*NSp floats = 5544960
#define GD_OFF   (PRED_OFF + NB*15*NSp*4)   // 6653984 ; NB*NBOX*10 floats
#define GI_OFF   (GD_OFF + NB*NBOX*10*4)    // 6685984 ; NB*NBOX*2 ints
#define WS_NEED  (GI_OFF + NB*NBOX*2*4)

__device__ __constant__ float c_AW[9] = {1.25f,2.0f,4.125f,3.75f,7.75f,7.375f,14.5f,19.5f,46.625f};
__device__ __constant__ float c_AH[9] = {1.625f,3.75f,2.875f,7.625f,5.625f,14.875f,11.25f,24.75f,40.75f};

__device__ __forceinline__ float safe_log(float p) {
    return fmaxf(logf(fmaxf(p, 1e-12f)), -100.0f);
}
__device__ __forceinline__ float sigm(float x) {
    return 1.0f / (1.0f + expf(-x));
}

// ---- Kernel 1: 15-channel GEMM + box decode -------------------------------
__global__ __launch_bounds__(256) void k_gemm15(
    const float* __restrict__ xin, const float* __restrict__ W,
    const float* __restrict__ bias, float* __restrict__ pred)
{
    const int s  = blockIdx.x * 256 + threadIdx.x;
    const int b  = blockIdx.y;
    const bool act = (s < NSp);
    const int ss = act ? s : 0;

    // channel rows needed: a*85 + {0..4}
    float acc[15];
#pragma unroll
    for (int f = 0; f < 15; f++) acc[f] = 0.f;

    const float* xp = xin + ((size_t)b * INCH) * NSp + ss;
#pragma unroll 4
    for (int c = 0; c < INCH; c++) {
        float v = xp[(size_t)c * NSp];
#pragma unroll
        for (int f = 0; f < 15; f++) {
            const int row = (f / 5) * NCg + (f % 5);   // compile-time
            acc[f] += W[row * INCH + c] * v;           // uniform -> s_load
        }
    }
    if (!act) return;

    const float gx = (float)(s % NGg);
    const float gy = (float)(s / NGg);

#pragma unroll
    for (int a = 0; a < 3; a++) {
        float x0 = acc[a*5+0] + bias[a*NCg+0];
        float x1 = acc[a*5+1] + bias[a*NCg+1];
        float x2 = acc[a*5+2] + bias[a*NCg+2];
        float x3 = acc[a*5+3] + bias[a*NCg+3];
        float x4 = acc[a*5+4] + bias[a*NCg+4];
        float px = sigm(x0) + gx;
        float py = sigm(x1) + gy;
        float pw = expf(x2) * c_AW[a];
        float ph = expf(x3) * c_AH[a];
        float cf = sigm(x4);
        size_t base = (((size_t)b*3 + a)*5) * NSp + s;
        pred[base + 0*NSp] = px;
        pred[base + 1*NSp] = py;
        pred[base + 2*NSp] = pw;
        pred[base + 3*NSp] = ph;
        pred[base + 4*NSp] = cf;
    }
}

// ---- Kernel 2: label processing + winner scatter --------------------------
__global__ void k_labels(const float* __restrict__ labels,
                         float* __restrict__ gdata, int* __restrict__ gint,
                         int* __restrict__ win)
{
    int t = blockIdx.x * blockDim.x + threadIdx.x;
    if (t >= NB * NBOX) return;
    int b = t / NBOX, n = t % NBOX;

    const float* L = labels + (size_t)t * 5;
    float l0 = L[0], l1 = L[1], l2 = L[2], l3 = L[3], l4 = L[4];
    int valid = (l0 + l1 + l2 + l3 + l4) > 0.f;

    float gx = l1 * NGg, gy = l2 * NGg, gw = l3 * NGg, gh = l4 * NGg;

    int best = 0; float brr = -1.f;
#pragma unroll
    for (int k = 0; k < 9; k++) {
        float inter = fminf(gw, c_AW[k]) * fminf(gh, c_AH[k]);
        float uni   = gw*gh + c_AW[k]*c_AH[k] - inter;
        float r     = inter / uni;
        if (r > brr) { brr = r; best = k; }   // first max wins (argmax)
    }
    int a = (best <= 2) ? best : -1;
    int assign = valid && (a >= 0);
    int a_safe = a < 0 ? 0 : (a > 2 ? 2 : a);

    float* gd = gdata + (size_t)t * 10;
    gd[0] = gx; gd[1] = gy; gd[2] = gw; gd[3] = gh;
    gd[4] = gx - floorf(gx);
    gd[5] = gy - floorf(gy);
    gd[6] = logf(gw / c_AW[a_safe] + 1e-16f);
    gd[7] = logf(gh / c_AH[a_safe] + 1e-16f);
    gd[8] = 2.f - gw * gh / (float)NSp;
    gd[9] = valid ? 1.f : 0.f;

    int gi = (int)floorf(gx), gj = (int)floorf(gy);
    int inb = (gi >= 0) && (gi < NGg) && (gj >= 0) && (gj < NGg);
    int cell = (assign && inb) ? (a * NSp + gj * NGg + gi) : -1;
    gint[t*2 + 0] = cell;
    gint[t*2 + 1] = (int)l0;

    if (cell >= 0) atomicMax(&win[b * NCELL + cell], n + 1);  // last index wins
}

// ---- Kernel 3: per-cell best-IoU + objectness BCE -------------------------
__global__ __launch_bounds__(256) void k_obj(
    const float* __restrict__ pred, const float* __restrict__ gdata,
    const int* __restrict__ win, float* __restrict__ acc)
{
    __shared__ float sb[NBOX][5];
    __shared__ int sHas;
    __shared__ float red[256];

    const int b = blockIdx.y;
    const int tid = threadIdx.x;

    if (tid < NBOX) {
        const float* gd = gdata + ((size_t)b * NBOX + tid) * 10;
        sb[tid][0] = gd[0]; sb[tid][1] = gd[1];
        sb[tid][2] = gd[2]; sb[tid][3] = gd[3];
        sb[tid][4] = gd[9];
    }
    if (tid == 0) sHas = 0;
    __syncthreads();
    if (tid < NBOX && sb[tid][4] > 0.f) atomicOr(&sHas, 1);
    __syncthreads();

    const int cell = blockIdx.x * 256 + tid;
    float l = 0.f;
    if (cell < NCELL) {
        int a = cell / NSp, s = cell % NSp;
        size_t pb = (((size_t)b*3 + a)*5) * NSp + s;
        float px = pred[pb + 0*NSp], py = pred[pb + 1*NSp];
        float pw = pred[pb + 2*NSp], ph = pred[pb + 3*NSp];
        float cf = pred[pb + 4*NSp];
        float pa = pw * ph;
        float bi = 0.f;
        for (int n = 0; n < NBOX; n++) {
            if (sb[n][4] > 0.f) {
                float gx = sb[n][0], gy = sb[n][1], gw = sb[n][2], gh = sb[n][3];
                float tlx = fmaxf(px - pw*0.5f, gx - gw*0.5f);
                float tly = fmaxf(py - ph*0.5f, gy - gh*0.5f);
                float brx = fminf(px + pw*0.5f, gx + gw*0.5f);
                float bry = fminf(py + ph*0.5f, gy + gh*0.5f);
                float inter = ((tlx < brx) && (tly < bry)) ? (brx-tlx)*(bry-tly) : 0.f;
                float iou = inter / (pa + gw*gh - inter);
                bi = fmaxf(bi, iou);
            }
        }
        bool maskpre  = sHas ? (bi <= 0.7f) : true;
        bool assigned = win[b * NCELL + cell] > 0;
        if (maskpre || assigned) {
            float t = assigned ? 1.f : 0.f;
            l = -(t * safe_log(cf) + (1.f - t) * safe_log(1.f - cf));
        }
    }
    red[tid] = l;
    __syncthreads();
    for (int o = 128; o > 0; o >>= 1) {
        if (tid < o) red[tid] += red[tid + o];
        __syncthreads();
    }
    if (tid == 0) atomicAdd(&acc[2], red[0]);
}

// ---- Kernel 4: per-assigned-cell xy/wh/cls losses -------------------------
__global__ __launch_bounds__(256) void k_assigned(
    const float* __restrict__ xin, const float* __restrict__ W,
    const float* __restrict__ bias, const float* __restrict__ gdata,
    const int* __restrict__ gint, const int* __restrict__ win,
    float* __restrict__ acc)
{
    const int t = blockIdx.x;            // box id 0..799
    const int b = t / NBOX, n = t % NBOX;
    const int cell = gint[t*2];
    if (cell < 0) return;
    if (win[b * NCELL + cell] != n + 1) return;   // only the winning box writes

    const int a = cell / NSp, s = cell % NSp;
    const int o0 = a * NCg;
    const int tid = threadIdx.x;

    __shared__ float4 col4[64];
    __shared__ float  xsh[NCg];
    __shared__ float  sacc[3];

    ((float*)col4)[tid] = xin[((size_t)b * INCH + tid) * NSp + s];
    if (tid < 3) sacc[tid] = 0.f;
    __syncthreads();

    const int wid = tid >> 6, lane = tid & 63;
    for (int o = wid; o < NCg; o += 4) {
        const float4 wv = *(const float4*)&W[(size_t)(o0 + o) * INCH + lane * 4];
        const float4 cv = col4[lane];
        float p = wv.x*cv.x + wv.y*cv.y + wv.z*cv.z + wv.w*cv.w;
        for (int off = 32; off; off >>= 1) p += __shfl_down(p, off);
        if (lane == 0) xsh[o] = p + bias[o0 + o];
    }
    __syncthreads();

    if (tid < NCg) {
        const float* gd = gdata + (size_t)t * 10;
        const float sval = gd[8];
        const int gcls = gint[t*2 + 1];
        float val = xsh[tid];
        float term; int slot;
        if (tid < 2) {                       // xy BCE * sval
            float tgt = gd[4 + tid];
            float p = sigm(val);
            term = -(tgt * safe_log(p) + (1.f - tgt) * safe_log(1.f - p)) * sval;
            slot = 0;
        } else if (tid < 4) {                // wh MSE * 0.5*sval
            float tgt = gd[4 + tid];         // gd[6], gd[7]
            float d = val - tgt;
            term = 0.5f * sval * d * d;
            slot = 1;
        } else if (tid == 4) {               // conf handled in k_obj
            term = 0.f; slot = 2;
        } else {                             // cls BCE
            float tgt = ((tid - 5) == gcls) ? 1.f : 0.f;
            float p = sigm(val);
            term = -(tgt * safe_log(p) + (1.f - tgt) * safe_log(1.f - p));
            slot = 2;
        }
        atomicAdd(&sacc[slot], term);
    }
    __syncthreads();
    if (tid == 0) {
        atomicAdd(&acc[0], sacc[0]);
        atomicAdd(&acc[1], sacc[1]);
        atomicAdd(&acc[3], sacc[2]);
    }
}

// ---- Kernel 5: finalize ---------------------------------------------------
__global__ void k_final(const float* __restrict__ acc, float* __restrict__ out)
{
    float xy = acc[0], wh = acc[1], ob = acc[2], cl = acc[3];
    out[0] = xy + wh + ob + cl;
    out[1] = xy; out[2] = wh; out[3] = ob; out[4] = cl;
}

extern "C" void kernel_launch(void* const* d_in, const int* in_sizes, int n_in,
                              void* d_out, int out_size, void* d_ws, size_t ws_size,
                              hipStream_t stream)
{
    const float* xin    = (const float*)d_in[0];
    const float* labels = (const float*)d_in[1];
    const float* W      = (const float*)d_in[2];
    const float* bias   = (const float*)d_in[3];

    char* ws = (char*)d_ws;
    float* acc   = (float*)(ws + ACC_OFF);
    int*   win   = (int*)  (ws + WIN_OFF);
    float* pred  = (float*)(ws + PRED_OFF);
    float* gdata = (float*)(ws + GD_OFF);
    int*   gint  = (int*)  (ws + GI_OFF);
    float* out   = (float*)d_out;

    // zero acc + winner array (ws is poisoned 0xAA before every call)
    hipMemsetAsync(ws, 0, PRED_OFF, stream);

    k_gemm15 <<<dim3((NSp + 255)/256, NB), 256, 0, stream>>>(xin, W, bias, pred);
    k_labels <<<dim3((NB*NBOX + 255)/256), 256, 0, stream>>>(labels, gdata, gint, win);
    k_obj    <<<dim3((NCELL + 255)/256, NB), 256, 0, stream>>>(pred, gdata, win, acc);
    k_assigned<<<dim3(NB*NBOX), 256, 0, stream>>>(xin, W, bias, gdata, gint, win, acc);
    k_final  <<<1, 1, 0, stream>>>(acc, out);
}

// Round 2
// 203.314 us; speedup vs baseline: 1.0989x; 1.0989x over previous
//
#include <hip/hip_runtime.h>
#include <math.h>

#define NB    16
#define NAg   3
#define NCg   85
#define NCLS  80
#define NGg   76
#define NSp   (NGg*NGg)     // 5776
#define NCELL (NAg*NSp)     // 17328
#define NBOX  50
#define INCH  256

// ws layout (bytes)
#define ACC_OFF  0                                  // 8 floats
#define WIN_OFF  32                                 // NB*NCELL ints   = 1,108,992
#define GD_OFF   (WIN_OFF + NB*NCELL*4)             // 1,109,024 ; NB*NBOX*10 floats = 32,000
#define GI_OFF   (GD_OFF + NB*NBOX*10*4)            // 1,141,024 ; NB*NBOX*2 ints    =  6,400
#define PART_OFF (GI_OFF + NB*NBOX*2*4)             // 1,147,424 ; NSLICE*NB*15*NSp floats
#define PART_SZ1 ((size_t)NB*15*NSp*4)              // 5,544,960 per slice
#define NEED4    (PART_OFF + 4*PART_SZ1)            // 23,327,264
#define NEED1    (PART_OFF + 1*PART_SZ1)            //  6,692,384 (== round-1 footprint)
#define ZERO_BYTES GD_OFF                           // acc + win

__device__ __constant__ float c_AW[9] = {1.25f,2.0f,4.125f,3.75f,7.75f,7.375f,14.5f,19.5f,46.625f};
__device__ __constant__ float c_AH[9] = {1.625f,3.75f,2.875f,7.625f,5.625f,14.875f,11.25f,24.75f,40.75f};

__device__ __forceinline__ float safe_log(float p) {
    return fmaxf(logf(fmaxf(p, 1e-12f)), -100.0f);
}
__device__ __forceinline__ float sigm(float x) {
    return 1.0f / (1.0f + expf(-x));
}

// ---- Kernel 1: partial 15-channel GEMM (channel-sliced, float4 spatial) ---
template<int NSLICE>
__global__ __launch_bounds__(256) void k_gemm_part(
    const float* __restrict__ xin, const float* __restrict__ W,
    float* __restrict__ part)
{
    constexpr int CPS = INCH / NSLICE;
    const int g  = blockIdx.x * 256 + threadIdx.x;   // float4 group id
    if (g >= NSp/4) return;
    const int b  = blockIdx.y;
    const int sl = blockIdx.z;
    const int s0 = g * 4;

    float4 acc[15];
#pragma unroll
    for (int f = 0; f < 15; f++) acc[f] = make_float4(0.f,0.f,0.f,0.f);

    const float* xp = xin + ((size_t)b * INCH + sl * CPS) * NSp + s0;
    const float* wp = W + sl * CPS;
#pragma unroll 8
    for (int c = 0; c < CPS; c++) {
        const float4 v = *(const float4*)(xp + (size_t)c * NSp);
#pragma unroll
        for (int f = 0; f < 15; f++) {
            const int row = (f / 5) * NCg + (f % 5);     // compile-time
            const float w = wp[row * INCH + c];          // wave-uniform -> s_load
            acc[f].x += w * v.x; acc[f].y += w * v.y;
            acc[f].z += w * v.z; acc[f].w += w * v.w;
        }
    }
#pragma unroll
    for (int f = 0; f < 15; f++)
        *(float4*)&part[(((size_t)sl * NB + b) * 15 + f) * NSp + s0] = acc[f];
}

// ---- Kernel 2: label processing + winner scatter --------------------------
__global__ void k_labels(const float* __restrict__ labels,
                         float* __restrict__ gdata, int* __restrict__ gint,
                         int* __restrict__ win)
{
    int t = blockIdx.x * blockDim.x + threadIdx.x;
    if (t >= NB * NBOX) return;
    int b = t / NBOX, n = t % NBOX;

    const float* L = labels + (size_t)t * 5;
    float l0 = L[0], l1 = L[1], l2 = L[2], l3 = L[3], l4 = L[4];
    int valid = (l0 + l1 + l2 + l3 + l4) > 0.f;

    float gx = l1 * NGg, gy = l2 * NGg, gw = l3 * NGg, gh = l4 * NGg;

    int best = 0; float brr = -1.f;
#pragma unroll
    for (int k = 0; k < 9; k++) {
        float inter = fminf(gw, c_AW[k]) * fminf(gh, c_AH[k]);
        float uni   = gw*gh + c_AW[k]*c_AH[k] - inter;
        float r     = inter / uni;
        if (r > brr) { brr = r; best = k; }   // first max wins (argmax)
    }
    int a = (best <= 2) ? best : -1;
    int assign = valid && (a >= 0);
    int a_safe = a < 0 ? 0 : (a > 2 ? 2 : a);

    float* gd = gdata + (size_t)t * 10;
    gd[0] = gx; gd[1] = gy; gd[2] = gw; gd[3] = gh;
    gd[4] = gx - floorf(gx);
    gd[5] = gy - floorf(gy);
    gd[6] = logf(gw / c_AW[a_safe] + 1e-16f);
    gd[7] = logf(gh / c_AH[a_safe] + 1e-16f);
    gd[8] = 2.f - gw * gh / (float)NSp;
    gd[9] = valid ? 1.f : 0.f;

    int gi = (int)floorf(gx), gj = (int)floorf(gy);
    int inb = (gi >= 0) && (gi < NGg) && (gj >= 0) && (gj < NGg);
    int cell = (assign && inb) ? (a * NSp + gj * NGg + gi) : -1;
    gint[t*2 + 0] = cell;
    gint[t*2 + 1] = (int)l0;

    if (cell >= 0) atomicMax(&win[b * NCELL + cell], n + 1);  // last index wins
}

// ---- Kernel 3: fused reduce + decode + best-IoU + obj BCE -----------------
template<int NSLICE>
__global__ __launch_bounds__(256) void k_fuse(
    const float* __restrict__ part, const float* __restrict__ bias,
    const float* __restrict__ gdata, const int* __restrict__ win,
    float* __restrict__ acc)
{
    __shared__ float sb[NBOX][5];
    __shared__ int sHas;
    __shared__ float red[256];

    const int b = blockIdx.y;
    const int tid = threadIdx.x;

    if (tid < NBOX) {
        const float* gd = gdata + ((size_t)b * NBOX + tid) * 10;
        sb[tid][0] = gd[0]; sb[tid][1] = gd[1];
        sb[tid][2] = gd[2]; sb[tid][3] = gd[3];
        sb[tid][4] = gd[9];
    }
    if (tid == 0) sHas = 0;
    __syncthreads();
    if (tid < NBOX && sb[tid][4] > 0.f) atomicOr(&sHas, 1);
    __syncthreads();

    const int cell = blockIdx.x * 256 + tid;
    float l = 0.f;
    if (cell < NCELL) {
        const int a = cell / NSp, s = cell % NSp;
        float x0 = 0.f, x1 = 0.f, x2 = 0.f, x3 = 0.f, x4 = 0.f;
#pragma unroll
        for (int sl = 0; sl < NSLICE; sl++) {
            const float* pp = part + (((size_t)sl * NB + b) * 15 + a * 5) * NSp + s;
            x0 += pp[0*NSp]; x1 += pp[1*NSp]; x2 += pp[2*NSp];
            x3 += pp[3*NSp]; x4 += pp[4*NSp];
        }
        const float gxf = (float)(s % NGg);
        const float gyf = (float)(s / NGg);
        float px = sigm(x0 + bias[a*NCg+0]) + gxf;
        float py = sigm(x1 + bias[a*NCg+1]) + gyf;
        float pw = expf(x2 + bias[a*NCg+2]) * c_AW[a];
        float ph = expf(x3 + bias[a*NCg+3]) * c_AH[a];
        float cf = sigm(x4 + bias[a*NCg+4]);
        float pa = pw * ph;
        float bi = 0.f;
        for (int n = 0; n < NBOX; n++) {
            if (sb[n][4] > 0.f) {
                float gx = sb[n][0], gy = sb[n][1], gw = sb[n][2], gh = sb[n][3];
                float tlx = fmaxf(px - pw*0.5f, gx - gw*0.5f);
                float tly = fmaxf(py - ph*0.5f, gy - gh*0.5f);
                float brx = fminf(px + pw*0.5f, gx + gw*0.5f);
                float bry = fminf(py + ph*0.5f, gy + gh*0.5f);
                float inter = ((tlx < brx) && (tly < bry)) ? (brx-tlx)*(bry-tly) : 0.f;
                float iou = inter / (pa + gw*gh - inter);
                bi = fmaxf(bi, iou);
            }
        }
        bool maskpre  = sHas ? (bi <= 0.7f) : true;
        bool assigned = win[b * NCELL + cell] > 0;
        if (maskpre || assigned) {
            float t = assigned ? 1.f : 0.f;
            l = -(t * safe_log(cf) + (1.f - t) * safe_log(1.f - cf));
        }
    }
    red[tid] = l;
    __syncthreads();
    for (int o = 128; o > 0; o >>= 1) {
        if (tid < o) red[tid] += red[tid + o];
        __syncthreads();
    }
    if (tid == 0) atomicAdd(&acc[2], red[0]);
}

// ---- Kernel 4: per-assigned-cell xy/wh/cls losses -------------------------
__global__ __launch_bounds__(256) void k_assigned(
    const float* __restrict__ xin, const float* __restrict__ W,
    const float* __restrict__ bias, const float* __restrict__ gdata,
    const int* __restrict__ gint, const int* __restrict__ win,
    float* __restrict__ acc)
{
    const int t = blockIdx.x;            // box id 0..799
    const int b = t / NBOX, n = t % NBOX;
    const int cell = gint[t*2];
    if (cell < 0) return;
    if (win[b * NCELL + cell] != n + 1) return;   // only the winning box writes

    const int a = cell / NSp, s = cell % NSp;
    const int o0 = a * NCg;
    const int tid = threadIdx.x;

    __shared__ float4 col4[64];
    __shared__ float  xsh[NCg];
    __shared__ float  sacc[3];

    ((float*)col4)[tid] = xin[((size_t)b * INCH + tid) * NSp + s];
    if (tid < 3) sacc[tid] = 0.f;
    __syncthreads();

    const int wid = tid >> 6, lane = tid & 63;
    for (int o = wid; o < NCg; o += 4) {
        const float4 wv = *(const float4*)&W[(size_t)(o0 + o) * INCH + lane * 4];
        const float4 cv = col4[lane];
        float p = wv.x*cv.x + wv.y*cv.y + wv.z*cv.z + wv.w*cv.w;
        for (int off = 32; off; off >>= 1) p += __shfl_down(p, off);
        if (lane == 0) xsh[o] = p + bias[o0 + o];
    }
    __syncthreads();

    if (tid < NCg) {
        const float* gd = gdata + (size_t)t * 10;
        const float sval = gd[8];
        const int gcls = gint[t*2 + 1];
        float val = xsh[tid];
        float term; int slot;
        if (tid < 2) {                       // xy BCE * sval
            float tgt = gd[4 + tid];
            float p = sigm(val);
            term = -(tgt * safe_log(p) + (1.f - tgt) * safe_log(1.f - p)) * sval;
            slot = 0;
        } else if (tid < 4) {                // wh MSE * 0.5*sval
            float tgt = gd[4 + tid];         // gd[6], gd[7]
            float d = val - tgt;
            term = 0.5f * sval * d * d;
            slot = 1;
        } else if (tid == 4) {               // conf handled in k_fuse
            term = 0.f; slot = 2;
        } else {                             // cls BCE
            float tgt = ((tid - 5) == gcls) ? 1.f : 0.f;
            float p = sigm(val);
            term = -(tgt * safe_log(p) + (1.f - tgt) * safe_log(1.f - p));
            slot = 2;
        }
        atomicAdd(&sacc[slot], term);
    }
    __syncthreads();
    if (tid == 0) {
        atomicAdd(&acc[0], sacc[0]);
        atomicAdd(&acc[1], sacc[1]);
        atomicAdd(&acc[3], sacc[2]);
    }
}

// ---- Kernel 5: finalize ---------------------------------------------------
__global__ void k_final(const float* __restrict__ acc, float* __restrict__ out)
{
    float xy = acc[0], wh = acc[1], ob = acc[2], cl = acc[3];
    out[0] = xy + wh + ob + cl;
    out[1] = xy; out[2] = wh; out[3] = ob; out[4] = cl;
}

extern "C" void kernel_launch(void* const* d_in, const int* in_sizes, int n_in,
                              void* d_out, int out_size, void* d_ws, size_t ws_size,
                              hipStream_t stream)
{
    const float* xin    = (const float*)d_in[0];
    const float* labels = (const float*)d_in[1];
    const float* W      = (const float*)d_in[2];
    const float* bias   = (const float*)d_in[3];

    char* ws = (char*)d_ws;
    float* acc   = (float*)(ws + ACC_OFF);
    int*   win   = (int*)  (ws + WIN_OFF);
    float* gdata = (float*)(ws + GD_OFF);
    int*   gint  = (int*)  (ws + GI_OFF);
    float* part  = (float*)(ws + PART_OFF);
    float* out   = (float*)d_out;

    const bool big = (ws_size >= (size_t)NEED4);

    hipMemsetAsync(ws, 0, ZERO_BYTES, stream);   // acc + win only

    k_labels<<<dim3((NB*NBOX + 255)/256), 256, 0, stream>>>(labels, gdata, gint, win);

    const int gx = (NSp/4 + 255) / 256;          // 6
    if (big) k_gemm_part<4><<<dim3(gx, NB, 4), 256, 0, stream>>>(xin, W, part);
    else     k_gemm_part<1><<<dim3(gx, NB, 1), 256, 0, stream>>>(xin, W, part);

    const int fx = (NCELL + 255) / 256;          // 68
    if (big) k_fuse<4><<<dim3(fx, NB), 256, 0, stream>>>(part, bias, gdata, win, acc);
    else     k_fuse<1><<<dim3(fx, NB), 256, 0, stream>>>(part, bias, gdata, win, acc);

    k_assigned<<<dim3(NB*NBOX), 256, 0, stream>>>(xin, W, bias, gdata, gint, win, acc);
    k_final<<<1, 1, 0, stream>>>(acc, out);
}